// Round 3
// baseline (283.151 us; speedup 1.0000x reference)
//
#include <hip/hip_runtime.h>

// N1=4097, N2=8192. y = x[1:].reshape(8192,4096); y[r,c] = x[r*4096+c+1]
// sum over r in [0,8191), c in [0,4095):
//   b[r,c] * (y[r,c] - prev^2)^2 ,  prev = y[r,c-1] (c>0) else y[r,4095]
// out = -a*(x[0]-mu)^2 - sum
//
// Round-3: WAVE-COALESCED loads. Rounds 0-2 all had lane-stride-64B
// addressing (each thread owning a contiguous 16-col chunk) -> every
// dwordx4 instruction bursts 64 distinct cache lines (4KB span), choking
// the per-CU miss queue at ~1.4 TB/s regardless of structure. Now lane i
// loads the contiguous float4 at base+16i (1KB/instruction, 16 lines,
// m13-copy shape) and the Rosenbrock chain crosses lanes via __shfl.
//
// Aligned-load trick: xv at float-index (r*4096 + c) holds
// {y[c-1], y[c], y[c+1], y[c+2]} for c = chunk_base + 4*lane, so terms
// for cols c..c+2 are lane-local; col c+3 needs y[c+3] = next lane's xv.x.

#define ROWS   8191u
#define GRID   2048
#define BLOCK  256
#define ROWSPB 4u            // rows per block; last block does 3

__global__ __launch_bounds__(BLOCK) void rosen_partial(
    const float* __restrict__ x, const float* __restrict__ b,
    float* __restrict__ partial)
{
    const unsigned lane = threadIdx.x & 63u;
    const unsigned w    = threadIdx.x >> 6;        // wave 0..3 : cols [1024w,1024w+1024)
    float acc = 0.0f;

    #pragma unroll 1
    for (unsigned k = 0; k < ROWSPB; ++k) {
        const unsigned r = blockIdx.x * ROWSPB + k;
        if (r >= ROWS) break;
        const size_t rowoff = (size_t)r * 4096u;
        const size_t base   = rowoff + w * 1024u + lane * 4u;

        // 8 fully-coalesced 1KB wave-loads (chunk stride = 256 floats)
        float4 xv0 = *(const float4*)(x + base);
        float4 xv1 = *(const float4*)(x + base + 256);
        float4 xv2 = *(const float4*)(x + base + 512);
        float4 xv3 = *(const float4*)(x + base + 768);
        float4 bv0 = *(const float4*)(b + base);
        float4 bv1 = *(const float4*)(b + base + 256);
        float4 bv2 = *(const float4*)(b + base + 512);
        float4 bv3 = *(const float4*)(b + base + 768);

        // wave-uniform tail: y[r, w*1024+1023] (one line/wave, broadcast)
        float tail = x[rowoff + w * 1024u + 1024u];
        // col-0 wrap (thread 0 only): prev = y[r,4095]
        float wrapv = 0.0f;
        if (threadIdx.x == 0) wrapv = x[rowoff + 4096u];
        // col 4095 excluded from the sum
        if (threadIdx.x == BLOCK - 1) bv3.w = 0.0f;

        // y[c+3] for each chunk: next lane's xv.x; lane 63 patches from
        // the next chunk's lane-0 value (or the wave tail for chunk 3).
        float n0 = __shfl_down(xv0.x, 1, 64);
        float n1 = __shfl_down(xv1.x, 1, 64);
        float n2 = __shfl_down(xv2.x, 1, 64);
        float n3 = __shfl_down(xv3.x, 1, 64);
        float c1 = __shfl(xv1.x, 0, 64);
        float c2 = __shfl(xv2.x, 0, 64);
        float c3 = __shfl(xv3.x, 0, 64);
        if (lane == 63u) { n0 = c1; n1 = c2; n2 = c3; n3 = tail; }

        float pv = xv0.x;
        if (threadIdx.x == 0) pv = wrapv;

        float d;
        // chunk 0
        d = xv0.y - pv    * pv;     acc += bv0.x * d * d;
        d = xv0.z - xv0.y * xv0.y;  acc += bv0.y * d * d;
        d = xv0.w - xv0.z * xv0.z;  acc += bv0.z * d * d;
        d = n0    - xv0.w * xv0.w;  acc += bv0.w * d * d;
        // chunk 1
        d = xv1.y - xv1.x * xv1.x;  acc += bv1.x * d * d;
        d = xv1.z - xv1.y * xv1.y;  acc += bv1.y * d * d;
        d = xv1.w - xv1.z * xv1.z;  acc += bv1.z * d * d;
        d = n1    - xv1.w * xv1.w;  acc += bv1.w * d * d;
        // chunk 2
        d = xv2.y - xv2.x * xv2.x;  acc += bv2.x * d * d;
        d = xv2.z - xv2.y * xv2.y;  acc += bv2.y * d * d;
        d = xv2.w - xv2.z * xv2.z;  acc += bv2.z * d * d;
        d = n2    - xv2.w * xv2.w;  acc += bv2.w * d * d;
        // chunk 3
        d = xv3.y - xv3.x * xv3.x;  acc += bv3.x * d * d;
        d = xv3.z - xv3.y * xv3.y;  acc += bv3.y * d * d;
        d = xv3.w - xv3.z * xv3.z;  acc += bv3.z * d * d;
        d = n3    - xv3.w * xv3.w;  acc += bv3.w * d * d;
    }

    // wave-64 + block reduction
    #pragma unroll
    for (int off = 32; off > 0; off >>= 1)
        acc += __shfl_down(acc, off, 64);

    __shared__ float sred[4];
    if (lane == 0) sred[w] = acc;
    __syncthreads();
    if (threadIdx.x == 0)
        partial[blockIdx.x] = sred[0] + sred[1] + sred[2] + sred[3];
}

__global__ __launch_bounds__(256) void rosen_final(const float* __restrict__ partial,
                                                   const float* __restrict__ x,
                                                   const float* __restrict__ a,
                                                   const float* __restrict__ mu,
                                                   float* __restrict__ out)
{
    float acc = 0.0f;
    for (int i = threadIdx.x; i < GRID; i += 256)
        acc += partial[i];

    #pragma unroll
    for (int off = 32; off > 0; off >>= 1)
        acc += __shfl_down(acc, off, 64);

    __shared__ float sred[4];
    const int lane = threadIdx.x & 63;
    const int wid  = threadIdx.x >> 6;
    if (lane == 0) sred[wid] = acc;
    __syncthreads();
    if (threadIdx.x == 0) {
        float total = sred[0] + sred[1] + sred[2] + sred[3];
        float dd = x[0] - mu[0];
        out[0] = -a[0] * dd * dd - total;
    }
}

extern "C" void kernel_launch(void* const* d_in, const int* in_sizes, int n_in,
                              void* d_out, int out_size, void* d_ws, size_t ws_size,
                              hipStream_t stream) {
    const float* x  = (const float*)d_in[0];
    const float* a  = (const float*)d_in[1];
    const float* b  = (const float*)d_in[2];
    const float* mu = (const float*)d_in[3];
    float* out     = (float*)d_out;
    float* partial = (float*)d_ws;   // GRID floats = 8 KB scratch

    rosen_partial<<<GRID, BLOCK, 0, stream>>>(x, b, partial);
    rosen_final<<<1, 256, 0, stream>>>(partial, x, a, mu, out);
}